// Round 2
// baseline (231.290 us; speedup 1.0000x reference)
//
#include <hip/hip_runtime.h>

// MultiBoxLoss (SSD). B=128, P=8732, C=21, N=16 (runtime-derived).
// R10: (a) k_pre restructured block-per-(b,split) SPLIT=8: each thread holds
//      all 16 boxes in registers + 16 running cross-mult argmaxes, scans its
//      split's priors ONCE (priors L2 traffic 286MB -> 17.9MB, corner math
//      amortized 16x). Writes per-split partial (in,un,idx); k_fused merges
//      the 8 partials in ascending split order (strict > keeps first index,
//      identical tie semantics to the old single-pass argmax).
//      (b) k_hard search loop: double-buffered count slots -> ONE barrier per
//      iteration instead of two (buf[i] read and buf[i+1] write disjoint;
//      buf[i] reuse fenced by barrier at i+1).
//      R9 kept: async LDS-DMA score staging (global_load_lds width=16).
// k_pre  : grid B*SPLIT; partial prior-argmax per (b,n); zeroes npos + acc.
// k_fused: thread per (b,p): merge pfo partials + match label + CE (C=21
//          unrolled) + SL1 + conf_neg; partials to locpart/pospart.
// k_hard : per-batch exact top-k (reg-resident 4-ary search on float bits);
//          one atomicAdd(acc_hard)/block + ticket; last block sums partials
//          and writes out[0].
// ws: slot[B*P] f32 conf_neg, npos[B] i32, pf_in/pf_un[B*SPLIT*MAXN] f32,
//     pf_id[B*SPLIT*MAXN] i32, locpart/pospart[B*nchunk] f32, acc[2].

#define MAXN 16
#define MAXE 16   // max ceil(P/1024) supported by k_hard
#define SPLIT 8   // prior-range splits in k_pre

__device__ __forceinline__ float sl1f(float d) {
    float ad = fabsf(d);
    return ad < 1.0f ? 0.5f * d * d : ad - 0.5f;
}

// One BLOCK (256 thr) per (b, split): partial argmax over this split's priors
// of IoU(box[b,n], prior) for ALL n simultaneously (boxes in registers).
// Quotient compare as cross-product: in/un > bi/bu <=> in*bu > bi*un (un,bu>0).
// Ascending p scan + strict > => first index on ties (matches jnp.argmax).
__global__ __launch_bounds__(256) void k_pre(
    const float* __restrict__ boxes,   // [B,N,4] xy
    const float* __restrict__ priors,  // [P,4] cxcy
    int P, int N,
    float* __restrict__ pf_in,         // [B*SPLIT*MAXN]
    float* __restrict__ pf_un,         // [B*SPLIT*MAXN]
    int*   __restrict__ pf_id,         // [B*SPLIT*MAXN]
    int* __restrict__ npos,            // [B] zeroed here
    float* __restrict__ acc)           // [2] zeroed here (hard, ticket)
{
    __shared__ float sbx1[MAXN], sby1[MAXN], sbx2[MAXN], sby2[MAXN], sba[MAXN];
    __shared__ float win[4][MAXN], wun[4][MAXN];
    __shared__ int   widd[4][MAXN];
    const int id = blockIdx.x;               // b*SPLIT + s
    const int tid = threadIdx.x;
    const int lane = tid & 63, w = tid >> 6;
    const int b = id / SPLIT, s = id % SPLIT;

    if (s == 0 && tid == 0) npos[b] = 0;
    if (id == 0 && tid < 2) ((unsigned*)acc)[tid] = 0u;
    if (N > MAXN) N = MAXN;

    if (tid < N) {
        const float* bp = boxes + ((size_t)b * N + tid) * 4;
        float x1 = bp[0], y1 = bp[1], x2 = bp[2], y2 = bp[3];
        sbx1[tid] = x1; sby1[tid] = y1; sbx2[tid] = x2; sby2[tid] = y2;
        sba[tid] = (x2 - x1) * (y2 - y1);
    }
    __syncthreads();

    // hoist boxes to registers (static indexing -> no scratch)
    float rx1[MAXN], ry1[MAXN], rx2[MAXN], ry2[MAXN], rar[MAXN];
#pragma unroll
    for (int n = 0; n < MAXN; n++) {
        if (n < N) { rx1[n]=sbx1[n]; ry1[n]=sby1[n]; rx2[n]=sbx2[n]; ry2[n]=sby2[n]; rar[n]=sba[n]; }
        else       { rx1[n]=0.f; ry1[n]=0.f; rx2[n]=0.f; ry2[n]=0.f; rar[n]=0.f; }
    }

    const int Q = (P + SPLIT - 1) / SPLIT;
    const int pbeg = s * Q;
    const int pend = min(pbeg + Q, P);

    float bi[MAXN], bu[MAXN]; int bx[MAXN];
#pragma unroll
    for (int n = 0; n < MAXN; n++) { bi[n] = -1.0f; bu[n] = 1.0f; bx[n] = 0x7fffffff; }

    for (int p = pbeg + tid; p < pend; p += 256) {
        float4 pr = ((const float4*)priors)[p];
        float px1 = pr.x - pr.z * 0.5f, py1 = pr.y - pr.w * 0.5f;
        float px2 = pr.x + pr.z * 0.5f, py2 = pr.y + pr.w * 0.5f;
        float parea = (px2 - px1) * (py2 - py1);
#pragma unroll
        for (int n = 0; n < MAXN; n++) {
            if (n < N) {
                float iw = fmaxf(fminf(rx2[n], px2) - fmaxf(rx1[n], px1), 0.0f);
                float ih = fmaxf(fminf(ry2[n], py2) - fmaxf(ry1[n], py1), 0.0f);
                float in = iw * ih;
                float un = rar[n] + parea - in;          // > 0
                if (in * bu[n] > bi[n] * un) { bi[n] = in; bu[n] = un; bx[n] = p; }
            }
        }
    }

    // per-wave reduce each n (prefer better ratio, then smaller index)
#pragma unroll
    for (int n = 0; n < MAXN; n++) {
        if (n < N) {
#pragma unroll
            for (int off = 32; off > 0; off >>= 1) {
                float oin = __shfl_down(bi[n], off);
                float oun = __shfl_down(bu[n], off);
                int   oid = __shfl_down(bx[n], off);
                float a = oin * bu[n], c = bi[n] * oun;
                if (a > c || (a == c && oid < bx[n])) { bi[n] = oin; bu[n] = oun; bx[n] = oid; }
            }
            if (lane == 0) { win[w][n] = bi[n]; wun[w][n] = bu[n]; widd[w][n] = bx[n]; }
        }
    }
    __syncthreads();
    if (tid < N) {
        const int n = tid;
        float fi = win[0][n], fu = wun[0][n]; int fx = widd[0][n];
        for (int ww = 1; ww < 4; ww++) {
            float oin = win[ww][n], oun = wun[ww][n]; int oid = widd[ww][n];
            float a = oin * fu, c = fi * oun;
            if (a > c || (a == c && oid < fx)) { fi = oin; fu = oun; fx = oid; }
        }
        const size_t o = ((size_t)b * SPLIT + s) * MAXN + n;
        pf_in[o] = fi; pf_un[o] = fu; pf_id[o] = fx;
    }
}

// Thread per (b,p), grid (nchunk, B). CT>0: compile-time class count.
template<int CT>
__global__ __launch_bounds__(256) void k_fused(
    const float* __restrict__ plocs,   // [B,P,4]
    const float* __restrict__ scores,  // [B*P, C]
    const float* __restrict__ boxes,   // [B,N,4]
    const int*   __restrict__ labels,  // [B,N]
    const float* __restrict__ priors,  // [P,4]
    const float* __restrict__ pf_in,   // [B*SPLIT*MAXN]
    const float* __restrict__ pf_un,
    const int*   __restrict__ pf_id,
    int P, int Crt, int N, int nchunk,
    float* __restrict__ conf_out,      // [B,P] conf_neg
    int*   __restrict__ npos,          // [B] (atomic, per-batch line)
    float* __restrict__ locpart,       // [B*nchunk]
    float* __restrict__ pospart)       // [B*nchunk]
{
    const int C = CT > 0 ? CT : Crt;
    extern __shared__ float sh[];      // 256*C floats (score rows)
    __shared__ float sx1[MAXN], sy1[MAXN], sx2[MAXN], sy2[MAXN], barea[MAXN];
    __shared__ int   blab[MAXN], spfo[MAXN];
    __shared__ float redf[4], redp[4];
    __shared__ int   redi[4];

    const int b = blockIdx.y;
    const int tid = threadIdx.x;
    const int lane = tid & 63, wid = tid >> 6;
    if (N > MAXN) N = MAXN;
    const int p0 = blockIdx.x * 256;
    const int rows = min(256, P - p0);

    if (tid < N) {
        const float* bp = boxes + ((size_t)b * N + tid) * 4;
        float x1 = bp[0], y1 = bp[1], x2 = bp[2], y2 = bp[3];
        sx1[tid] = x1; sy1[tid] = y1; sx2[tid] = x2; sy2[tid] = y2;
        barea[tid] = (x2 - x1) * (y2 - y1);
        blab[tid] = labels[(size_t)b * N + tid];
        // merge SPLIT partial argmax records (ascending split order; within a
        // split idx ascends, so strict > keeps the globally-first index on ties)
        const size_t base = (size_t)b * SPLIT * MAXN + tid;
        float fi = pf_in[base], fu = pf_un[base]; int fx = pf_id[base];
#pragma unroll
        for (int sp = 1; sp < SPLIT; sp++) {
            float oin = pf_in[base + (size_t)sp * MAXN];
            float oun = pf_un[base + (size_t)sp * MAXN];
            int   oid = pf_id[base + (size_t)sp * MAXN];
            if (oin * fu > fi * oun) { fi = oin; fu = oun; fx = oid; }
        }
        spfo[tid] = fx;
    }

    // Stage this block's score rows into LDS.
    // Fast path: async LDS-DMA, 1KB per instr (64 lanes x 16B), wave-uniform
    // LDS base + lane*16 (linear layout, HW rule), per-lane global src.
    {
        const size_t f4base = ((size_t)b * P + p0) * C / 4;
        const int f4cnt = (rows * C + 3) / 4;
        const float4* __restrict__ s4 = (const float4*)scores + f4base;
        if ((P & 3) == 0) {
            for (int c = wid; c * 64 < f4cnt; c += 4) {     // c wave-uniform
                int idx = c * 64 + lane;
                if (idx < f4cnt) {                           // exec-masked tail
                    __builtin_amdgcn_global_load_lds(
                        (const __attribute__((address_space(1))) void*)(s4 + idx),
                        (__attribute__((address_space(3))) void*)((char*)sh + (size_t)c * 1024),
                        16, 0, 0);
                }
            }
            asm volatile("s_waitcnt vmcnt(0)" ::: "memory");
        } else {
            // fallback: sync copy (bit-identical layout)
            for (int j = tid; j < f4cnt; j += 256)
                ((float4*)sh)[j] = s4[j];
        }
    }
    __syncthreads();

    const int p = p0 + tid;
    float locs = 0.0f, posc = 0.0f, conf = 0.0f;
    int np = 0;
    if (p < P) {
        float4 pr = ((const float4*)priors)[p];
        float px1 = pr.x - pr.z * 0.5f, py1 = pr.y - pr.w * 0.5f;
        float px2 = pr.x + pr.z * 0.5f, py2 = pr.y + pr.w * 0.5f;
        float parea = (px2 - px1) * (py2 - py1);
        float bi = -1.0f, bu = 1.0f; int bestn = 0;
#pragma unroll
        for (int n = 0; n < MAXN; n++) {
            if (n < N) {
                float iw = fmaxf(fminf(sx2[n], px2) - fmaxf(sx1[n], px1), 0.0f);
                float ih = fmaxf(fminf(sy2[n], py2) - fmaxf(sy1[n], py1), 0.0f);
                float in = iw * ih;
                float un = barea[n] + parea - in;
                if (in * bu > bi * un) { bi = in; bu = un; bestn = n; }
            }
        }
        // override: last n with pfo[n]==p wins (matches sequential scatter)
#pragma unroll
        for (int n = 0; n < MAXN; n++) {
            if (n < N && spfo[n] == p) { bestn = n; bi = 1.0f; bu = 1.0f; }
        }
        const int lab = (bi < 0.5f * bu) ? 0 : blab[bestn];  // iou < 0.5

        // CE from staged row (serial order preserved; unrolled when CT>0)
        const float* r = sh + tid * C;
        float m = -3.402823466e38f;
#pragma unroll
        for (int c = 0; c < C; c++) m = fmaxf(m, r[c]);
        float sum = 0.0f;
#pragma unroll
        for (int c = 0; c < C; c++) sum += __expf(r[c] - m);
        float ce = m + __logf(sum) - r[lab];   // -log_softmax[lab]

        if (lab != 0) {
            posc = ce; np = 1;
            int n = bestn;
            float cx = (sx1[n] + sx2[n]) * 0.5f, cy = (sy1[n] + sy2[n]) * 0.5f;
            float w = sx2[n] - sx1[n], h = sy2[n] - sy1[n];
            float g0 = (cx - pr.x) / (pr.z / 10.0f);
            float g1 = (cy - pr.y) / (pr.w / 10.0f);
            float g2 = logf(w / pr.z) * 5.0f;
            float g3 = logf(h / pr.w) * 5.0f;
            float4 pl = ((const float4*)plocs)[(size_t)b * P + p];
            locs = sl1f(pl.x - g0) + sl1f(pl.y - g1) + sl1f(pl.z - g2) + sl1f(pl.w - g3);
        } else {
            conf = ce;
        }
        conf_out[(size_t)b * P + p] = conf;
    }
#pragma unroll
    for (int off = 32; off > 0; off >>= 1) {
        locs += __shfl_down(locs, off);
        posc += __shfl_down(posc, off);
        np   += __shfl_down(np, off);
    }
    if (lane == 0) { redf[wid] = locs; redp[wid] = posc; redi[wid] = np; }
    __syncthreads();
    if (tid == 0) {
        float L = redf[0] + redf[1] + redf[2] + redf[3];
        float Pp = redp[0] + redp[1] + redp[2] + redp[3];
        int   c = redi[0] + redi[1] + redi[2] + redi[3];
        if (c) atomicAdd(&npos[b], c);            // per-batch line: cheap
        locpart[b * nchunk + blockIdx.x] = L;     // plain stores: deterministic
        pospart[b * nchunk + blockIdx.x] = Pp;
    }
}

// Per-batch exact top-k sum; register-resident values; 4-ary search on float
// bit patterns (conf >= 0 so uint order == float order). Double-buffered count
// slots -> ONE barrier per search iteration. One atomicAdd per block to acc[0]
// (128 total) + ticket in acc[1]; last block sums the k_fused partials (plain
// loads, kernel-boundary visible) and writes out[0].
__global__ __launch_bounds__(1024, 4) void k_hard(
    const float* __restrict__ conf,     // [B,P] conf_neg
    const int* __restrict__ npos,       // [B]
    const float* __restrict__ locpart,  // [nloc]
    const float* __restrict__ pospart,  // [nloc]
    int P, int B, int nloc,
    float* __restrict__ acc,            // [2]: hard sum, ticket
    float* __restrict__ out)
{
    __shared__ int   redi[2][16 * 3];   // double-buffered per-wave counts
    __shared__ float redf2[16];
    __shared__ int   redi2[16];
    __shared__ float rl[16], rp[16];
    __shared__ int   rn[16], is_last;
    const int b = blockIdx.x, tid = threadIdx.x;
    const int lane = tid & 63, wid = tid >> 6;
    const int nthr = blockDim.x, nw = nthr >> 6;
    const int ne = (P + nthr - 1) / nthr;        // 9 for P=8732
    long long kk = (long long)npos[b] * 3;
    int k = kk > P ? P : (int)kk;                // block-uniform

    float S = 0.0f;
    if (k > 0) {
        // Coalesced load into registers; sentinel 0 (search thresholds >= 1,
        // final pass strict > t with t >= 0 -> never selected).
        unsigned e[MAXE];
#pragma unroll
        for (int j = 0; j < MAXE; j++) {
            int p = j * nthr + tid;
            e[j] = (j < ne && p < P) ? __float_as_uint(conf[(size_t)b * P + p]) : 0u;
        }

        // largest bit pattern t with count(x >= t) >= k == exact k-th largest
        unsigned lo = 0u, hi = 0x7F800000u;
        int itp = 0;                              // buffer parity
        while (lo < hi) {
            int* buf = redi[itp & 1]; itp++;
            unsigned span = hi - lo;
            if (span >= 8) {
                unsigned q = span >> 2;
                unsigned m1 = lo + q, m2 = lo + 2 * q, m3 = lo + 3 * q;
                int c1 = 0, c2 = 0, c3 = 0;
#pragma unroll
                for (int j = 0; j < MAXE; j++) {
                    if (j < ne) {
                        unsigned v = e[j];
                        c1 += (int)__popcll(__ballot(v >= m1));
                        c2 += (int)__popcll(__ballot(v >= m2));
                        c3 += (int)__popcll(__ballot(v >= m3));
                    }
                }
                if (lane == 0) {
                    buf[wid * 3 + 0] = c1; buf[wid * 3 + 1] = c2; buf[wid * 3 + 2] = c3;
                }
                __syncthreads();                 // single barrier per iteration
                int C1 = 0, C2 = 0, C3 = 0;
                for (int w = 0; w < nw; w++) {
                    C1 += buf[w * 3 + 0]; C2 += buf[w * 3 + 1]; C3 += buf[w * 3 + 2];
                }
                if      (C3 >= k) lo = m3;
                else if (C2 >= k) { lo = m2; hi = m3 - 1; }
                else if (C1 >= k) { lo = m1; hi = m2 - 1; }
                else              hi = m1 - 1;
            } else {
                unsigned mid = lo + ((span + 1) >> 1);
                int c = 0;
#pragma unroll
                for (int j = 0; j < MAXE; j++)
                    if (j < ne) c += (int)__popcll(__ballot(e[j] >= mid));
                if (lane == 0) buf[wid * 3] = c;
                __syncthreads();
                int Cc = 0;
                for (int w = 0; w < nw; w++) Cc += buf[w * 3];
                if (Cc >= k) lo = mid; else hi = mid - 1;
            }
        }
        __syncthreads();   // all waves done reading last buf before reuse below

        float t = __uint_as_float(lo);
        float sgt = 0.0f; int cgt = 0;
#pragma unroll
        for (int j = 0; j < MAXE; j++) {
            if (j < ne) {
                float v = __uint_as_float(e[j]);
                if (v > t) { sgt += v; cgt++; }
            }
        }
#pragma unroll
        for (int off = 32; off > 0; off >>= 1) {
            sgt += __shfl_down(sgt, off);
            cgt += __shfl_down(cgt, off);
        }
        if (lane == 0) { redf2[wid] = sgt; redi2[wid] = cgt; }
        __syncthreads();
        if (tid == 0) {
            int Cg = 0;
            for (int w = 0; w < nw; w++) { S += redf2[w]; Cg += redi2[w]; }
            S += (float)(k - Cg) * t;   // ties at t handled exactly
        }
        __syncthreads();
    }

    if (tid == 0) {
        atomicAdd(&acc[0], S);                   // 128 adds total: ~1.5us
        __threadfence();
        unsigned tk = atomicAdd((unsigned*)(acc + 1), 1u);
        is_last = (tk == (unsigned)gridDim.x - 1) ? 1 : 0;
    }
    __syncthreads();
    if (is_last) {
        float lp = 0.0f, pp = 0.0f; int np = 0;
        for (int i = tid; i < nloc; i += nthr) { lp += locpart[i]; pp += pospart[i]; }
        for (int i = tid; i < B; i += nthr) np += npos[i];
#pragma unroll
        for (int off = 32; off > 0; off >>= 1) {
            lp += __shfl_down(lp, off);
            pp += __shfl_down(pp, off);
            np += __shfl_down(np, off);
        }
        if (lane == 0) { rl[wid] = lp; rp[wid] = pp; rn[wid] = np; }
        __syncthreads();
        if (tid == 0) {
            float L = 0.0f, Pp = 0.0f; int Np = 0;
            for (int w = 0; w < nw; w++) { L += rl[w]; Pp += rp[w]; Np += rn[w]; }
            float hard = atomicAdd(&acc[0], 0.0f);   // device-coherent read
            float npf = (float)Np;
            out[0] = (hard + Pp) / npf + L / (npf * 4.0f);
        }
    }
}

extern "C" void kernel_launch(void* const* d_in, const int* in_sizes, int n_in,
                              void* d_out, int out_size, void* d_ws, size_t ws_size,
                              hipStream_t stream)
{
    const float* plocs  = (const float*)d_in[0];
    const float* scores = (const float*)d_in[1];
    const float* boxes  = (const float*)d_in[2];
    const int*   labels = (const int*)d_in[3];
    const float* priors = (const float*)d_in[4];

    int P = in_sizes[4] / 4;
    int B = in_sizes[0] / (P * 4);
    int C = in_sizes[1] / (in_sizes[0] / 4);
    int N = in_sizes[3] / B;
    int nchunk = (P + 255) / 256;
    int nloc = B * nchunk;

    char* w = (char*)d_ws;
    float* slot    = (float*)w;  w += (size_t)B * P * sizeof(float);
    int*   npos    = (int*)w;    w += (size_t)B * sizeof(int);
    float* pf_in   = (float*)w;  w += (size_t)B * SPLIT * MAXN * sizeof(float);
    float* pf_un   = (float*)w;  w += (size_t)B * SPLIT * MAXN * sizeof(float);
    int*   pf_id   = (int*)w;    w += (size_t)B * SPLIT * MAXN * sizeof(int);
    float* locpart = (float*)w;  w += (size_t)nloc * sizeof(float);
    float* pospart = (float*)w;  w += (size_t)nloc * sizeof(float);
    w = (char*)(((uintptr_t)w + 63) & ~(uintptr_t)63);
    float* acc     = (float*)w;  // 2 words

    k_pre<<<B * SPLIT, 256, 0, stream>>>(boxes, priors, P, N,
                                         pf_in, pf_un, pf_id, npos, acc);

    dim3 ga(nchunk, B);
    size_t smf = (size_t)256 * C * sizeof(float);
    if (C == 21) {
        k_fused<21><<<ga, 256, smf, stream>>>(plocs, scores, boxes, labels, priors,
                                              pf_in, pf_un, pf_id, P, C, N, nchunk,
                                              slot, npos, locpart, pospart);
    } else {
        k_fused<0><<<ga, 256, smf, stream>>>(plocs, scores, boxes, labels, priors,
                                             pf_in, pf_un, pf_id, P, C, N, nchunk,
                                             slot, npos, locpart, pospart);
    }

    k_hard<<<B, 1024, 0, stream>>>(slot, npos, locpart, pospart,
                                   P, B, nloc, acc, (float*)d_out);
}

// Round 3
// 219.233 us; speedup vs baseline: 1.0550x; 1.0550x over previous
//
#include <hip/hip_runtime.h>

// MultiBoxLoss (SSD). B=128, P=8732, C=21, N=16 (runtime-derived).
// R11: R10's k_pre regressed +24us (16-box register state ~128 VGPR -> spill/
//      occupancy cliff). Recovery: block per (b, box-group-of-4), SPLIT=1 --
//      scans ALL P priors once for 4 boxes (priors L2 traffic 286->71.7MB,
//      corner math amortized 4x) with only ~32 live state VGPRs. pfo interface
//      identical to R9, so k_fused is R9 verbatim. k_hard keeps R10's
//      single-barrier double-buffered search (safe WAR ordering, -1us).
//      R9 kept: async LDS-DMA score staging (global_load_lds width=16).
// k_pre  : grid B*ceil(N/4); full prior-argmax for 4 boxes; zeroes npos+acc.
// k_fused: thread per (b,p): match label + CE (C=21 unrolled) + SL1 +
//          conf_neg; partials to locpart/pospart; npos[b] int atomic.
// k_hard : per-batch exact top-k (reg-resident 4-ary search on float bits);
//          one atomicAdd(acc_hard)/block + ticket; last block sums partials
//          and writes out[0].
// ws: slot[B*P] f32 conf_neg, npos[B] i32, pfo[B*N] i32,
//     locpart[B*nchunk] f32, pospart[B*nchunk] f32, acc[2] (hard f32, ticket).

#define MAXN 16
#define MAXE 16   // max ceil(P/1024) supported by k_hard
#define NB 4      // boxes per k_pre block (low register pressure)

__device__ __forceinline__ float sl1f(float d) {
    float ad = fabsf(d);
    return ad < 1.0f ? 0.5f * d * d : ad - 0.5f;
}

// One BLOCK (256 thr) per (b, box-group of NB): argmax over ALL P priors of
// IoU(box[b,n], prior) for the group's boxes simultaneously (boxes in regs).
// Quotient compare as cross-product: in/un > bi/bu <=> in*bu > bi*un (un,bu>0).
// Ascending p scan + strict > => first index on ties (matches jnp.argmax).
__global__ __launch_bounds__(256) void k_pre(
    const float* __restrict__ boxes,   // [B,N,4] xy
    const float* __restrict__ priors,  // [P,4] cxcy
    int P, int N, int ngrp,
    int* __restrict__ pfo,             // [B*N]
    int* __restrict__ npos,            // [B] zeroed here
    float* __restrict__ acc)           // [2] zeroed here (hard, ticket)
{
    __shared__ float sbx[NB * 5];                // x1,y1,x2,y2,area per box
    __shared__ float win[4][NB], wun[4][NB];
    __shared__ int   widd[4][NB];
    const int id = blockIdx.x;                   // b*ngrp + g
    const int tid = threadIdx.x;
    const int lane = tid & 63, w = tid >> 6;
    const int b = id / ngrp, g = id % ngrp;
    const int n0 = g * NB;
    const int nb = min(NB, N - n0);

    if (tid == 0 && g == 0) npos[b] = 0;
    if (id == 0 && tid < 2) ((unsigned*)acc)[tid] = 0u;

    if (tid < nb) {
        const float* bp = boxes + ((size_t)b * N + n0 + tid) * 4;
        float x1 = bp[0], y1 = bp[1], x2 = bp[2], y2 = bp[3];
        sbx[tid * 5 + 0] = x1; sbx[tid * 5 + 1] = y1;
        sbx[tid * 5 + 2] = x2; sbx[tid * 5 + 3] = y2;
        sbx[tid * 5 + 4] = (x2 - x1) * (y2 - y1);
    }
    __syncthreads();

    float rx1[NB], ry1[NB], rx2[NB], ry2[NB], rar[NB];
#pragma unroll
    for (int j = 0; j < NB; j++) {
        if (j < nb) {
            rx1[j] = sbx[j * 5 + 0]; ry1[j] = sbx[j * 5 + 1];
            rx2[j] = sbx[j * 5 + 2]; ry2[j] = sbx[j * 5 + 3];
            rar[j] = sbx[j * 5 + 4];
        } else { rx1[j] = ry1[j] = rx2[j] = ry2[j] = rar[j] = 0.0f; }
    }

    float bi[NB], bu[NB]; int bx[NB];
#pragma unroll
    for (int j = 0; j < NB; j++) { bi[j] = -1.0f; bu[j] = 1.0f; bx[j] = 0x7fffffff; }

#pragma unroll 2
    for (int p = tid; p < P; p += 256) {
        float4 pr = ((const float4*)priors)[p];
        float px1 = pr.x - pr.z * 0.5f, py1 = pr.y - pr.w * 0.5f;
        float px2 = pr.x + pr.z * 0.5f, py2 = pr.y + pr.w * 0.5f;
        float parea = (px2 - px1) * (py2 - py1);
#pragma unroll
        for (int j = 0; j < NB; j++) {
            if (j < nb) {
                float iw = fmaxf(fminf(rx2[j], px2) - fmaxf(rx1[j], px1), 0.0f);
                float ih = fmaxf(fminf(ry2[j], py2) - fmaxf(ry1[j], py1), 0.0f);
                float in = iw * ih;
                float un = rar[j] + parea - in;          // > 0
                if (in * bu[j] > bi[j] * un) { bi[j] = in; bu[j] = un; bx[j] = p; }
            }
        }
    }

    // per-wave reduce each j (prefer better ratio, then smaller index)
#pragma unroll
    for (int j = 0; j < NB; j++) {
        if (j < nb) {
#pragma unroll
            for (int off = 32; off > 0; off >>= 1) {
                float oin = __shfl_down(bi[j], off);
                float oun = __shfl_down(bu[j], off);
                int   oid = __shfl_down(bx[j], off);
                float a = oin * bu[j], c = bi[j] * oun;
                if (a > c || (a == c && oid < bx[j])) { bi[j] = oin; bu[j] = oun; bx[j] = oid; }
            }
            if (lane == 0) { win[w][j] = bi[j]; wun[w][j] = bu[j]; widd[w][j] = bx[j]; }
        }
    }
    __syncthreads();
    if (tid < nb) {
        const int j = tid;
        float fi = win[0][j], fu = wun[0][j]; int fx = widd[0][j];
        for (int ww = 1; ww < 4; ww++) {
            float oin = win[ww][j], oun = wun[ww][j]; int oid = widd[ww][j];
            float a = oin * fu, c = fi * oun;
            if (a > c || (a == c && oid < fx)) { fi = oin; fu = oun; fx = oid; }
        }
        pfo[b * N + n0 + j] = fx;
    }
}

// Thread per (b,p), grid (nchunk, B). CT>0: compile-time class count.
template<int CT>
__global__ __launch_bounds__(256) void k_fused(
    const float* __restrict__ plocs,   // [B,P,4]
    const float* __restrict__ scores,  // [B*P, C]
    const float* __restrict__ boxes,   // [B,N,4]
    const int*   __restrict__ labels,  // [B,N]
    const float* __restrict__ priors,  // [P,4]
    const int*   __restrict__ pfo,     // [B*N]
    int P, int Crt, int N, int nchunk,
    float* __restrict__ conf_out,      // [B,P] conf_neg
    int*   __restrict__ npos,          // [B] (atomic, per-batch line)
    float* __restrict__ locpart,       // [B*nchunk]
    float* __restrict__ pospart)       // [B*nchunk]
{
    const int C = CT > 0 ? CT : Crt;
    extern __shared__ float sh[];      // 256*C floats (score rows)
    __shared__ float sx1[MAXN], sy1[MAXN], sx2[MAXN], sy2[MAXN], barea[MAXN];
    __shared__ int   blab[MAXN], spfo[MAXN];
    __shared__ float redf[4], redp[4];
    __shared__ int   redi[4];

    const int b = blockIdx.y;
    const int tid = threadIdx.x;
    const int lane = tid & 63, wid = tid >> 6;
    if (N > MAXN) N = MAXN;
    const int p0 = blockIdx.x * 256;
    const int rows = min(256, P - p0);

    if (tid < N) {
        const float* bp = boxes + ((size_t)b * N + tid) * 4;
        float x1 = bp[0], y1 = bp[1], x2 = bp[2], y2 = bp[3];
        sx1[tid] = x1; sy1[tid] = y1; sx2[tid] = x2; sy2[tid] = y2;
        barea[tid] = (x2 - x1) * (y2 - y1);
        blab[tid] = labels[(size_t)b * N + tid];
        spfo[tid] = pfo[b * N + tid];
    }

    // Stage this block's score rows into LDS.
    // Fast path: async LDS-DMA, 1KB per instr (64 lanes x 16B), wave-uniform
    // LDS base + lane*16 (linear layout, HW rule), per-lane global src.
    {
        const size_t f4base = ((size_t)b * P + p0) * C / 4;
        const int f4cnt = (rows * C + 3) / 4;
        const float4* __restrict__ s4 = (const float4*)scores + f4base;
        if ((P & 3) == 0) {
            for (int c = wid; c * 64 < f4cnt; c += 4) {     // c wave-uniform
                int idx = c * 64 + lane;
                if (idx < f4cnt) {                           // exec-masked tail
                    __builtin_amdgcn_global_load_lds(
                        (const __attribute__((address_space(1))) void*)(s4 + idx),
                        (__attribute__((address_space(3))) void*)((char*)sh + (size_t)c * 1024),
                        16, 0, 0);
                }
            }
            asm volatile("s_waitcnt vmcnt(0)" ::: "memory");
        } else {
            // fallback: sync copy (bit-identical layout)
            for (int j = tid; j < f4cnt; j += 256)
                ((float4*)sh)[j] = s4[j];
        }
    }
    __syncthreads();

    const int p = p0 + tid;
    float locs = 0.0f, posc = 0.0f, conf = 0.0f;
    int np = 0;
    if (p < P) {
        float4 pr = ((const float4*)priors)[p];
        float px1 = pr.x - pr.z * 0.5f, py1 = pr.y - pr.w * 0.5f;
        float px2 = pr.x + pr.z * 0.5f, py2 = pr.y + pr.w * 0.5f;
        float parea = (px2 - px1) * (py2 - py1);
        float bi = -1.0f, bu = 1.0f; int bestn = 0;
#pragma unroll
        for (int n = 0; n < MAXN; n++) {
            if (n < N) {
                float iw = fmaxf(fminf(sx2[n], px2) - fmaxf(sx1[n], px1), 0.0f);
                float ih = fmaxf(fminf(sy2[n], py2) - fmaxf(sy1[n], py1), 0.0f);
                float in = iw * ih;
                float un = barea[n] + parea - in;
                if (in * bu > bi * un) { bi = in; bu = un; bestn = n; }
            }
        }
        // override: last n with pfo[n]==p wins (matches sequential scatter)
#pragma unroll
        for (int n = 0; n < MAXN; n++) {
            if (n < N && spfo[n] == p) { bestn = n; bi = 1.0f; bu = 1.0f; }
        }
        const int lab = (bi < 0.5f * bu) ? 0 : blab[bestn];  // iou < 0.5

        // CE from staged row (serial order preserved; unrolled when CT>0)
        const float* r = sh + tid * C;
        float m = -3.402823466e38f;
#pragma unroll
        for (int c = 0; c < C; c++) m = fmaxf(m, r[c]);
        float sum = 0.0f;
#pragma unroll
        for (int c = 0; c < C; c++) sum += __expf(r[c] - m);
        float ce = m + __logf(sum) - r[lab];   // -log_softmax[lab]

        if (lab != 0) {
            posc = ce; np = 1;
            int n = bestn;
            float cx = (sx1[n] + sx2[n]) * 0.5f, cy = (sy1[n] + sy2[n]) * 0.5f;
            float w = sx2[n] - sx1[n], h = sy2[n] - sy1[n];
            float g0 = (cx - pr.x) / (pr.z / 10.0f);
            float g1 = (cy - pr.y) / (pr.w / 10.0f);
            float g2 = logf(w / pr.z) * 5.0f;
            float g3 = logf(h / pr.w) * 5.0f;
            float4 pl = ((const float4*)plocs)[(size_t)b * P + p];
            locs = sl1f(pl.x - g0) + sl1f(pl.y - g1) + sl1f(pl.z - g2) + sl1f(pl.w - g3);
        } else {
            conf = ce;
        }
        conf_out[(size_t)b * P + p] = conf;
    }
#pragma unroll
    for (int off = 32; off > 0; off >>= 1) {
        locs += __shfl_down(locs, off);
        posc += __shfl_down(posc, off);
        np   += __shfl_down(np, off);
    }
    if (lane == 0) { redf[wid] = locs; redp[wid] = posc; redi[wid] = np; }
    __syncthreads();
    if (tid == 0) {
        float L = redf[0] + redf[1] + redf[2] + redf[3];
        float Pp = redp[0] + redp[1] + redp[2] + redp[3];
        int   c = redi[0] + redi[1] + redi[2] + redi[3];
        if (c) atomicAdd(&npos[b], c);            // per-batch line: cheap
        locpart[b * nchunk + blockIdx.x] = L;     // plain stores: deterministic
        pospart[b * nchunk + blockIdx.x] = Pp;
    }
}

// Per-batch exact top-k sum; register-resident values; 4-ary search on float
// bit patterns (conf >= 0 so uint order == float order). Double-buffered count
// slots -> ONE barrier per search iteration. One atomicAdd per block to acc[0]
// (128 total) + ticket in acc[1]; last block sums the k_fused partials (plain
// loads, kernel-boundary visible) and writes out[0].
__global__ __launch_bounds__(1024, 4) void k_hard(
    const float* __restrict__ conf,     // [B,P] conf_neg
    const int* __restrict__ npos,       // [B]
    const float* __restrict__ locpart,  // [nloc]
    const float* __restrict__ pospart,  // [nloc]
    int P, int B, int nloc,
    float* __restrict__ acc,            // [2]: hard sum, ticket
    float* __restrict__ out)
{
    __shared__ int   redi[2][16 * 3];   // double-buffered per-wave counts
    __shared__ float redf2[16];
    __shared__ int   redi2[16];
    __shared__ float rl[16], rp[16];
    __shared__ int   rn[16], is_last;
    const int b = blockIdx.x, tid = threadIdx.x;
    const int lane = tid & 63, wid = tid >> 6;
    const int nthr = blockDim.x, nw = nthr >> 6;
    const int ne = (P + nthr - 1) / nthr;        // 9 for P=8732
    long long kk = (long long)npos[b] * 3;
    int k = kk > P ? P : (int)kk;                // block-uniform

    float S = 0.0f;
    if (k > 0) {
        // Coalesced load into registers; sentinel 0 (search thresholds >= 1,
        // final pass strict > t with t >= 0 -> never selected).
        unsigned e[MAXE];
#pragma unroll
        for (int j = 0; j < MAXE; j++) {
            int p = j * nthr + tid;
            e[j] = (j < ne && p < P) ? __float_as_uint(conf[(size_t)b * P + p]) : 0u;
        }

        // largest bit pattern t with count(x >= t) >= k == exact k-th largest
        unsigned lo = 0u, hi = 0x7F800000u;
        int itp = 0;                              // buffer parity
        while (lo < hi) {
            int* buf = redi[itp & 1]; itp++;
            unsigned span = hi - lo;
            if (span >= 8) {
                unsigned q = span >> 2;
                unsigned m1 = lo + q, m2 = lo + 2 * q, m3 = lo + 3 * q;
                int c1 = 0, c2 = 0, c3 = 0;
#pragma unroll
                for (int j = 0; j < MAXE; j++) {
                    if (j < ne) {
                        unsigned v = e[j];
                        c1 += (int)__popcll(__ballot(v >= m1));
                        c2 += (int)__popcll(__ballot(v >= m2));
                        c3 += (int)__popcll(__ballot(v >= m3));
                    }
                }
                if (lane == 0) {
                    buf[wid * 3 + 0] = c1; buf[wid * 3 + 1] = c2; buf[wid * 3 + 2] = c3;
                }
                __syncthreads();                 // single barrier per iteration
                int C1 = 0, C2 = 0, C3 = 0;
                for (int w = 0; w < nw; w++) {
                    C1 += buf[w * 3 + 0]; C2 += buf[w * 3 + 1]; C3 += buf[w * 3 + 2];
                }
                if      (C3 >= k) lo = m3;
                else if (C2 >= k) { lo = m2; hi = m3 - 1; }
                else if (C1 >= k) { lo = m1; hi = m2 - 1; }
                else              hi = m1 - 1;
            } else {
                unsigned mid = lo + ((span + 1) >> 1);
                int c = 0;
#pragma unroll
                for (int j = 0; j < MAXE; j++)
                    if (j < ne) c += (int)__popcll(__ballot(e[j] >= mid));
                if (lane == 0) buf[wid * 3] = c;
                __syncthreads();
                int Cc = 0;
                for (int w = 0; w < nw; w++) Cc += buf[w * 3];
                if (Cc >= k) lo = mid; else hi = mid - 1;
            }
        }
        __syncthreads();   // all waves done reading last buf before reuse below

        float t = __uint_as_float(lo);
        float sgt = 0.0f; int cgt = 0;
#pragma unroll
        for (int j = 0; j < MAXE; j++) {
            if (j < ne) {
                float v = __uint_as_float(e[j]);
                if (v > t) { sgt += v; cgt++; }
            }
        }
#pragma unroll
        for (int off = 32; off > 0; off >>= 1) {
            sgt += __shfl_down(sgt, off);
            cgt += __shfl_down(cgt, off);
        }
        if (lane == 0) { redf2[wid] = sgt; redi2[wid] = cgt; }
        __syncthreads();
        if (tid == 0) {
            int Cg = 0;
            for (int w = 0; w < nw; w++) { S += redf2[w]; Cg += redi2[w]; }
            S += (float)(k - Cg) * t;   // ties at t handled exactly
        }
        __syncthreads();
    }

    if (tid == 0) {
        atomicAdd(&acc[0], S);                   // 128 adds total: ~1.5us
        __threadfence();
        unsigned tk = atomicAdd((unsigned*)(acc + 1), 1u);
        is_last = (tk == (unsigned)gridDim.x - 1) ? 1 : 0;
    }
    __syncthreads();
    if (is_last) {
        float lp = 0.0f, pp = 0.0f; int np = 0;
        for (int i = tid; i < nloc; i += nthr) { lp += locpart[i]; pp += pospart[i]; }
        for (int i = tid; i < B; i += nthr) np += npos[i];
#pragma unroll
        for (int off = 32; off > 0; off >>= 1) {
            lp += __shfl_down(lp, off);
            pp += __shfl_down(pp, off);
            np += __shfl_down(np, off);
        }
        if (lane == 0) { rl[wid] = lp; rp[wid] = pp; rn[wid] = np; }
        __syncthreads();
        if (tid == 0) {
            float L = 0.0f, Pp = 0.0f; int Np = 0;
            for (int w = 0; w < nw; w++) { L += rl[w]; Pp += rp[w]; Np += rn[w]; }
            float hard = atomicAdd(&acc[0], 0.0f);   // device-coherent read
            float npf = (float)Np;
            out[0] = (hard + Pp) / npf + L / (npf * 4.0f);
        }
    }
}

extern "C" void kernel_launch(void* const* d_in, const int* in_sizes, int n_in,
                              void* d_out, int out_size, void* d_ws, size_t ws_size,
                              hipStream_t stream)
{
    const float* plocs  = (const float*)d_in[0];
    const float* scores = (const float*)d_in[1];
    const float* boxes  = (const float*)d_in[2];
    const int*   labels = (const int*)d_in[3];
    const float* priors = (const float*)d_in[4];

    int P = in_sizes[4] / 4;
    int B = in_sizes[0] / (P * 4);
    int C = in_sizes[1] / (in_sizes[0] / 4);
    int N = in_sizes[3] / B;
    int nchunk = (P + 255) / 256;
    int nloc = B * nchunk;
    int BN = B * N;
    int ngrp = (N + NB - 1) / NB;

    char* w = (char*)d_ws;
    float* slot    = (float*)w;  w += (size_t)B * P * sizeof(float);
    int*   npos    = (int*)w;    w += (size_t)B * sizeof(int);
    int*   pfo     = (int*)w;    w += (size_t)BN * sizeof(int);
    float* locpart = (float*)w;  w += (size_t)nloc * sizeof(float);
    float* pospart = (float*)w;  w += (size_t)nloc * sizeof(float);
    w = (char*)(((uintptr_t)w + 63) & ~(uintptr_t)63);
    float* acc     = (float*)w;  // 2 words

    k_pre<<<B * ngrp, 256, 0, stream>>>(boxes, priors, P, N, ngrp, pfo, npos, acc);

    dim3 ga(nchunk, B);
    size_t smf = (size_t)256 * C * sizeof(float);
    if (C == 21) {
        k_fused<21><<<ga, 256, smf, stream>>>(plocs, scores, boxes, labels, priors,
                                              pfo, P, C, N, nchunk, slot, npos,
                                              locpart, pospart);
    } else {
        k_fused<0><<<ga, 256, smf, stream>>>(plocs, scores, boxes, labels, priors,
                                             pfo, P, C, N, nchunk, slot, npos,
                                             locpart, pospart);
    }

    k_hard<<<B, 1024, 0, stream>>>(slot, npos, locpart, pospart,
                                   P, B, nloc, acc, (float*)d_out);
}

// Round 4
// 207.441 us; speedup vs baseline: 1.1150x; 1.0568x over previous
//
#include <hip/hip_runtime.h>

// MultiBoxLoss (SSD). B=128, P=8732, C=21, N=16 (runtime-derived).
// R12: single change vs R9 (206.9us, best measured): k_pre keeps R9's 2048-
//      block grid (8 blocks/CU, full TLP) but each block now owns a (box-PAIR,
//      prior-HALF): 2 boxes x P/2 priors. Priors L2 traffic 286->143MB, corner
//      math amortized 2x, ~16 state VGPRs (no spill risk, unlike R10/R11 which
//      cut the grid 4-16x and regressed). Half-partials (in,un,idx) merged in
//      k_fused's 16-thread init (half0 first + strict > == first-index ties).
//      k_fused: R9 verbatim (async LDS-DMA score staging, width=16).
//      k_hard : R9 verbatim (two-barrier search; R10's 1-barrier variant was a
//               confounded variable, reverted for clean attribution).
// ws: slot[B*P] f32 conf_neg, npos[B] i32, pf_in/pf_un/pf_id[B*KP_SP*MAXN],
//     locpart/pospart[B*nchunk] f32, acc[2] (hard f32, ticket).

#define MAXN 16
#define MAXE 16   // max ceil(P/1024) supported by k_hard
#define KP_NB 2   // boxes per k_pre block
#define KP_SP 2   // prior-range splits per box-pair

__device__ __forceinline__ float sl1f(float d) {
    float ad = fabsf(d);
    return ad < 1.0f ? 0.5f * d * d : ad - 0.5f;
}

// One BLOCK (256 thr) per (b, box-pair, prior-half): partial argmax over this
// half's priors of IoU(box[b,n], prior) for the pair's boxes (boxes in regs).
// Quotient compare as cross-product: in/un > bi/bu <=> in*bu > bi*un (un,bu>0).
// Ascending p scan + strict > => first index on ties (matches jnp.argmax).
__global__ __launch_bounds__(256) void k_pre(
    const float* __restrict__ boxes,   // [B,N,4] xy
    const float* __restrict__ priors,  // [P,4] cxcy
    int P, int N, int npair,
    float* __restrict__ pf_in,         // [B*KP_SP*MAXN]
    float* __restrict__ pf_un,         // [B*KP_SP*MAXN]
    int*   __restrict__ pf_id,         // [B*KP_SP*MAXN]
    int* __restrict__ npos,            // [B] zeroed here
    float* __restrict__ acc)           // [2] zeroed here (hard, ticket)
{
    __shared__ float win[4][KP_NB], wun[4][KP_NB];
    __shared__ int   widd[4][KP_NB];
    const int id = blockIdx.x;                   // b*(npair*KP_SP) + pr*KP_SP + h
    const int tid = threadIdx.x;
    const int lane = tid & 63, w = tid >> 6;
    const int per_b = npair * KP_SP;
    const int b = id / per_b, rem = id % per_b;
    const int pr = rem / KP_SP, h = rem % KP_SP;
    const int n0 = pr * KP_NB;
    const int nb = min(KP_NB, N - n0);

    if (tid == 0 && rem == 0) npos[b] = 0;
    if (id == 0 && tid < 2) ((unsigned*)acc)[tid] = 0u;

    // broadcast-load the pair's boxes (block-uniform addresses -> scalar loads)
    float rx1[KP_NB], ry1[KP_NB], rx2[KP_NB], ry2[KP_NB], rar[KP_NB];
#pragma unroll
    for (int j = 0; j < KP_NB; j++) {
        const int n = n0 + (j < nb ? j : 0);     // clamp (dup harmless, not stored)
        const float* bp = boxes + ((size_t)b * N + n) * 4;
        rx1[j] = bp[0]; ry1[j] = bp[1]; rx2[j] = bp[2]; ry2[j] = bp[3];
        rar[j] = (rx2[j] - rx1[j]) * (ry2[j] - ry1[j]);
    }

    const int Q = (P + KP_SP - 1) / KP_SP;
    const int pbeg = h * Q;
    const int pend = min(pbeg + Q, P);

    float bi[KP_NB], bu[KP_NB]; int bx[KP_NB];
#pragma unroll
    for (int j = 0; j < KP_NB; j++) { bi[j] = -1.0f; bu[j] = 1.0f; bx[j] = 0x7fffffff; }

#pragma unroll 2
    for (int p = pbeg + tid; p < pend; p += 256) {
        float4 prr = ((const float4*)priors)[p];
        float px1 = prr.x - prr.z * 0.5f, py1 = prr.y - prr.w * 0.5f;
        float px2 = prr.x + prr.z * 0.5f, py2 = prr.y + prr.w * 0.5f;
        float parea = (px2 - px1) * (py2 - py1);
#pragma unroll
        for (int j = 0; j < KP_NB; j++) {
            float iw = fmaxf(fminf(rx2[j], px2) - fmaxf(rx1[j], px1), 0.0f);
            float ih = fmaxf(fminf(ry2[j], py2) - fmaxf(ry1[j], py1), 0.0f);
            float in = iw * ih;
            float un = rar[j] + parea - in;          // > 0
            if (in * bu[j] > bi[j] * un) { bi[j] = in; bu[j] = un; bx[j] = p; }
        }
    }

    // per-wave reduce each j (prefer better ratio, then smaller index)
#pragma unroll
    for (int j = 0; j < KP_NB; j++) {
#pragma unroll
        for (int off = 32; off > 0; off >>= 1) {
            float oin = __shfl_down(bi[j], off);
            float oun = __shfl_down(bu[j], off);
            int   oid = __shfl_down(bx[j], off);
            float a = oin * bu[j], c = bi[j] * oun;
            if (a > c || (a == c && oid < bx[j])) { bi[j] = oin; bu[j] = oun; bx[j] = oid; }
        }
        if (lane == 0) { win[w][j] = bi[j]; wun[w][j] = bu[j]; widd[w][j] = bx[j]; }
    }
    __syncthreads();
    if (tid == 0) {
#pragma unroll
        for (int j = 0; j < KP_NB; j++) {
            float fi = win[0][j], fu = wun[0][j]; int fx = widd[0][j];
            for (int ww = 1; ww < 4; ww++) {
                float oin = win[ww][j], oun = wun[ww][j]; int oid = widd[ww][j];
                float a = oin * fu, c = fi * oun;
                if (a > c || (a == c && oid < fx)) { fi = oin; fu = oun; fx = oid; }
            }
            if (j < nb) {
                const size_t o = ((size_t)b * KP_SP + h) * MAXN + n0 + j;
                pf_in[o] = fi; pf_un[o] = fu; pf_id[o] = fx;
            }
        }
    }
}

// Thread per (b,p), grid (nchunk, B). CT>0: compile-time class count.
template<int CT>
__global__ __launch_bounds__(256) void k_fused(
    const float* __restrict__ plocs,   // [B,P,4]
    const float* __restrict__ scores,  // [B*P, C]
    const float* __restrict__ boxes,   // [B,N,4]
    const int*   __restrict__ labels,  // [B,N]
    const float* __restrict__ priors,  // [P,4]
    const float* __restrict__ pf_in,   // [B*KP_SP*MAXN]
    const float* __restrict__ pf_un,
    const int*   __restrict__ pf_id,
    int P, int Crt, int N, int nchunk,
    float* __restrict__ conf_out,      // [B,P] conf_neg
    int*   __restrict__ npos,          // [B] (atomic, per-batch line)
    float* __restrict__ locpart,       // [B*nchunk]
    float* __restrict__ pospart)       // [B*nchunk]
{
    const int C = CT > 0 ? CT : Crt;
    extern __shared__ float sh[];      // 256*C floats (score rows)
    __shared__ float sx1[MAXN], sy1[MAXN], sx2[MAXN], sy2[MAXN], barea[MAXN];
    __shared__ int   blab[MAXN], spfo[MAXN];
    __shared__ float redf[4], redp[4];
    __shared__ int   redi[4];

    const int b = blockIdx.y;
    const int tid = threadIdx.x;
    const int lane = tid & 63, wid = tid >> 6;
    if (N > MAXN) N = MAXN;
    const int p0 = blockIdx.x * 256;
    const int rows = min(256, P - p0);

    if (tid < N) {
        const float* bp = boxes + ((size_t)b * N + tid) * 4;
        float x1 = bp[0], y1 = bp[1], x2 = bp[2], y2 = bp[3];
        sx1[tid] = x1; sy1[tid] = y1; sx2[tid] = x2; sy2[tid] = y2;
        barea[tid] = (x2 - x1) * (y2 - y1);
        blab[tid] = labels[(size_t)b * N + tid];
        // merge the KP_SP half-partials (half0 first + strict > => the
        // globally-first index on cross-mult ties, same semantics as R9)
        const size_t base = (size_t)b * KP_SP * MAXN + tid;
        float fi = pf_in[base], fu = pf_un[base]; int fx = pf_id[base];
#pragma unroll
        for (int sp = 1; sp < KP_SP; sp++) {
            float oin = pf_in[base + (size_t)sp * MAXN];
            float oun = pf_un[base + (size_t)sp * MAXN];
            int   oid = pf_id[base + (size_t)sp * MAXN];
            if (oin * fu > fi * oun) { fi = oin; fu = oun; fx = oid; }
        }
        spfo[tid] = fx;
    }

    // Stage this block's score rows into LDS.
    // Fast path: async LDS-DMA, 1KB per instr (64 lanes x 16B), wave-uniform
    // LDS base + lane*16 (linear layout, HW rule), per-lane global src.
    {
        const size_t f4base = ((size_t)b * P + p0) * C / 4;
        const int f4cnt = (rows * C + 3) / 4;
        const float4* __restrict__ s4 = (const float4*)scores + f4base;
        if ((P & 3) == 0) {
            for (int c = wid; c * 64 < f4cnt; c += 4) {     // c wave-uniform
                int idx = c * 64 + lane;
                if (idx < f4cnt) {                           // exec-masked tail
                    __builtin_amdgcn_global_load_lds(
                        (const __attribute__((address_space(1))) void*)(s4 + idx),
                        (__attribute__((address_space(3))) void*)((char*)sh + (size_t)c * 1024),
                        16, 0, 0);
                }
            }
            asm volatile("s_waitcnt vmcnt(0)" ::: "memory");
        } else {
            // fallback: sync copy (bit-identical layout)
            for (int j = tid; j < f4cnt; j += 256)
                ((float4*)sh)[j] = s4[j];
        }
    }
    __syncthreads();

    const int p = p0 + tid;
    float locs = 0.0f, posc = 0.0f, conf = 0.0f;
    int np = 0;
    if (p < P) {
        float4 pr = ((const float4*)priors)[p];
        float px1 = pr.x - pr.z * 0.5f, py1 = pr.y - pr.w * 0.5f;
        float px2 = pr.x + pr.z * 0.5f, py2 = pr.y + pr.w * 0.5f;
        float parea = (px2 - px1) * (py2 - py1);
        float bi = -1.0f, bu = 1.0f; int bestn = 0;
#pragma unroll
        for (int n = 0; n < MAXN; n++) {
            if (n < N) {
                float iw = fmaxf(fminf(sx2[n], px2) - fmaxf(sx1[n], px1), 0.0f);
                float ih = fmaxf(fminf(sy2[n], py2) - fmaxf(sy1[n], py1), 0.0f);
                float in = iw * ih;
                float un = barea[n] + parea - in;
                if (in * bu > bi * un) { bi = in; bu = un; bestn = n; }
            }
        }
        // override: last n with pfo[n]==p wins (matches sequential scatter)
#pragma unroll
        for (int n = 0; n < MAXN; n++) {
            if (n < N && spfo[n] == p) { bestn = n; bi = 1.0f; bu = 1.0f; }
        }
        const int lab = (bi < 0.5f * bu) ? 0 : blab[bestn];  // iou < 0.5

        // CE from staged row (serial order preserved; unrolled when CT>0)
        const float* r = sh + tid * C;
        float m = -3.402823466e38f;
#pragma unroll
        for (int c = 0; c < C; c++) m = fmaxf(m, r[c]);
        float sum = 0.0f;
#pragma unroll
        for (int c = 0; c < C; c++) sum += __expf(r[c] - m);
        float ce = m + __logf(sum) - r[lab];   // -log_softmax[lab]

        if (lab != 0) {
            posc = ce; np = 1;
            int n = bestn;
            float cx = (sx1[n] + sx2[n]) * 0.5f, cy = (sy1[n] + sy2[n]) * 0.5f;
            float w = sx2[n] - sx1[n], h = sy2[n] - sy1[n];
            float g0 = (cx - pr.x) / (pr.z / 10.0f);
            float g1 = (cy - pr.y) / (pr.w / 10.0f);
            float g2 = logf(w / pr.z) * 5.0f;
            float g3 = logf(h / pr.w) * 5.0f;
            float4 pl = ((const float4*)plocs)[(size_t)b * P + p];
            locs = sl1f(pl.x - g0) + sl1f(pl.y - g1) + sl1f(pl.z - g2) + sl1f(pl.w - g3);
        } else {
            conf = ce;
        }
        conf_out[(size_t)b * P + p] = conf;
    }
#pragma unroll
    for (int off = 32; off > 0; off >>= 1) {
        locs += __shfl_down(locs, off);
        posc += __shfl_down(posc, off);
        np   += __shfl_down(np, off);
    }
    if (lane == 0) { redf[wid] = locs; redp[wid] = posc; redi[wid] = np; }
    __syncthreads();
    if (tid == 0) {
        float L = redf[0] + redf[1] + redf[2] + redf[3];
        float Pp = redp[0] + redp[1] + redp[2] + redp[3];
        int   c = redi[0] + redi[1] + redi[2] + redi[3];
        if (c) atomicAdd(&npos[b], c);            // per-batch line: cheap
        locpart[b * nchunk + blockIdx.x] = L;     // plain stores: deterministic
        pospart[b * nchunk + blockIdx.x] = Pp;
    }
}

// Per-batch exact top-k sum; register-resident values; 4-ary search on float
// bit patterns (conf >= 0 so uint order == float order). One atomicAdd per
// block to acc[0] (128 total) + ticket in acc[1]; last block sums the
// k_fused partials (plain loads, kernel-boundary visible) and writes out[0].
__global__ __launch_bounds__(1024, 4) void k_hard(
    const float* __restrict__ conf,     // [B,P] conf_neg
    const int* __restrict__ npos,       // [B]
    const float* __restrict__ locpart,  // [nloc]
    const float* __restrict__ pospart,  // [nloc]
    int P, int B, int nloc,
    float* __restrict__ acc,            // [2]: hard sum, ticket
    float* __restrict__ out)
{
    __shared__ int   redi[16 * 3];
    __shared__ float redf2[16];
    __shared__ int   redi2[16];
    __shared__ float rl[16], rp[16];
    __shared__ int   rn[16], is_last;
    const int b = blockIdx.x, tid = threadIdx.x;
    const int lane = tid & 63, wid = tid >> 6;
    const int nthr = blockDim.x, nw = nthr >> 6;
    const int ne = (P + nthr - 1) / nthr;        // 9 for P=8732
    long long kk = (long long)npos[b] * 3;
    int k = kk > P ? P : (int)kk;                // block-uniform

    float S = 0.0f;
    if (k > 0) {
        // Coalesced load into registers; sentinel 0 (search thresholds >= 1,
        // final pass strict > t with t >= 0 -> never selected).
        unsigned e[MAXE];
#pragma unroll
        for (int j = 0; j < MAXE; j++) {
            int p = j * nthr + tid;
            e[j] = (j < ne && p < P) ? __float_as_uint(conf[(size_t)b * P + p]) : 0u;
        }

        // largest bit pattern t with count(x >= t) >= k == exact k-th largest
        unsigned lo = 0u, hi = 0x7F800000u;
        while (lo < hi) {
            unsigned span = hi - lo;
            if (span >= 8) {
                unsigned q = span >> 2;
                unsigned m1 = lo + q, m2 = lo + 2 * q, m3 = lo + 3 * q;
                int c1 = 0, c2 = 0, c3 = 0;
#pragma unroll
                for (int j = 0; j < MAXE; j++) {
                    if (j < ne) {
                        unsigned v = e[j];
                        c1 += (int)__popcll(__ballot(v >= m1));
                        c2 += (int)__popcll(__ballot(v >= m2));
                        c3 += (int)__popcll(__ballot(v >= m3));
                    }
                }
                if (lane == 0) {
                    redi[wid * 3 + 0] = c1; redi[wid * 3 + 1] = c2; redi[wid * 3 + 2] = c3;
                }
                __syncthreads();
                int C1 = 0, C2 = 0, C3 = 0;
                for (int w = 0; w < nw; w++) {
                    C1 += redi[w * 3 + 0]; C2 += redi[w * 3 + 1]; C3 += redi[w * 3 + 2];
                }
                __syncthreads();
                if      (C3 >= k) lo = m3;
                else if (C2 >= k) { lo = m2; hi = m3 - 1; }
                else if (C1 >= k) { lo = m1; hi = m2 - 1; }
                else              hi = m1 - 1;
            } else {
                unsigned mid = lo + ((span + 1) >> 1);
                int c = 0;
#pragma unroll
                for (int j = 0; j < MAXE; j++)
                    if (j < ne) c += (int)__popcll(__ballot(e[j] >= mid));
                if (lane == 0) redi[wid * 3] = c;
                __syncthreads();
                int Cc = 0;
                for (int w = 0; w < nw; w++) Cc += redi[w * 3];
                __syncthreads();
                if (Cc >= k) lo = mid; else hi = mid - 1;
            }
        }

        float t = __uint_as_float(lo);
        float sgt = 0.0f; int cgt = 0;
#pragma unroll
        for (int j = 0; j < MAXE; j++) {
            if (j < ne) {
                float v = __uint_as_float(e[j]);
                if (v > t) { sgt += v; cgt++; }
            }
        }
#pragma unroll
        for (int off = 32; off > 0; off >>= 1) {
            sgt += __shfl_down(sgt, off);
            cgt += __shfl_down(cgt, off);
        }
        if (lane == 0) { redf2[wid] = sgt; redi2[wid] = cgt; }
        __syncthreads();
        if (tid == 0) {
            int Cg = 0;
            for (int w = 0; w < nw; w++) { S += redf2[w]; Cg += redi2[w]; }
            S += (float)(k - Cg) * t;   // ties at t handled exactly
        }
        __syncthreads();
    }

    if (tid == 0) {
        atomicAdd(&acc[0], S);                   // 128 adds total: ~1.5us
        __threadfence();
        unsigned tk = atomicAdd((unsigned*)(acc + 1), 1u);
        is_last = (tk == (unsigned)gridDim.x - 1) ? 1 : 0;
    }
    __syncthreads();
    if (is_last) {
        float lp = 0.0f, pp = 0.0f; int np = 0;
        for (int i = tid; i < nloc; i += nthr) { lp += locpart[i]; pp += pospart[i]; }
        for (int i = tid; i < B; i += nthr) np += npos[i];
#pragma unroll
        for (int off = 32; off > 0; off >>= 1) {
            lp += __shfl_down(lp, off);
            pp += __shfl_down(pp, off);
            np += __shfl_down(np, off);
        }
        if (lane == 0) { rl[wid] = lp; rp[wid] = pp; rn[wid] = np; }
        __syncthreads();
        if (tid == 0) {
            float L = 0.0f, Pp = 0.0f; int Np = 0;
            for (int w = 0; w < nw; w++) { L += rl[w]; Pp += rp[w]; Np += rn[w]; }
            float hard = atomicAdd(&acc[0], 0.0f);   // device-coherent read
            float npf = (float)Np;
            out[0] = (hard + Pp) / npf + L / (npf * 4.0f);
        }
    }
}

extern "C" void kernel_launch(void* const* d_in, const int* in_sizes, int n_in,
                              void* d_out, int out_size, void* d_ws, size_t ws_size,
                              hipStream_t stream)
{
    const float* plocs  = (const float*)d_in[0];
    const float* scores = (const float*)d_in[1];
    const float* boxes  = (const float*)d_in[2];
    const int*   labels = (const int*)d_in[3];
    const float* priors = (const float*)d_in[4];

    int P = in_sizes[4] / 4;
    int B = in_sizes[0] / (P * 4);
    int C = in_sizes[1] / (in_sizes[0] / 4);
    int N = in_sizes[3] / B;
    int nchunk = (P + 255) / 256;
    int nloc = B * nchunk;
    int npair = (N + KP_NB - 1) / KP_NB;

    char* w = (char*)d_ws;
    float* slot    = (float*)w;  w += (size_t)B * P * sizeof(float);
    int*   npos    = (int*)w;    w += (size_t)B * sizeof(int);
    float* pf_in   = (float*)w;  w += (size_t)B * KP_SP * MAXN * sizeof(float);
    float* pf_un   = (float*)w;  w += (size_t)B * KP_SP * MAXN * sizeof(float);
    int*   pf_id   = (int*)w;    w += (size_t)B * KP_SP * MAXN * sizeof(int);
    float* locpart = (float*)w;  w += (size_t)nloc * sizeof(float);
    float* pospart = (float*)w;  w += (size_t)nloc * sizeof(float);
    w = (char*)(((uintptr_t)w + 63) & ~(uintptr_t)63);
    float* acc     = (float*)w;  // 2 words

    k_pre<<<B * npair * KP_SP, 256, 0, stream>>>(boxes, priors, P, N, npair,
                                                 pf_in, pf_un, pf_id, npos, acc);

    dim3 ga(nchunk, B);
    size_t smf = (size_t)256 * C * sizeof(float);
    if (C == 21) {
        k_fused<21><<<ga, 256, smf, stream>>>(plocs, scores, boxes, labels, priors,
                                              pf_in, pf_un, pf_id, P, C, N, nchunk,
                                              slot, npos, locpart, pospart);
    } else {
        k_fused<0><<<ga, 256, smf, stream>>>(plocs, scores, boxes, labels, priors,
                                             pf_in, pf_un, pf_id, P, C, N, nchunk,
                                             slot, npos, locpart, pospart);
    }

    k_hard<<<B, 1024, 0, stream>>>(slot, npos, locpart, pospart,
                                   P, B, nloc, acc, (float*)d_out);
}